// Round 13
// baseline (147.953 us; speedup 1.0000x reference)
//
#include <hip/hip_runtime.h>

#define CCH 192
#define HWN 16384
#define NB  4
#define SPLIT 32

typedef __attribute__((ext_vector_type(8))) short bf16x8;
typedef __attribute__((ext_vector_type(4))) float f32x4;

// swizzled fragment-native layout for a [R rows][C cols] bf16 matrix:
//   idx(r,c) = (r>>4)*(16*C) + (c>>3)*128 + (r&15)*8 + (c&7)

__device__ __forceinline__ ushort f2bf(float f) {
  union { float f; unsigned u; } v; v.f = f;
  return (ushort)((v.u + 0x7fffu + ((v.u >> 16) & 1u)) >> 16);
}

__device__ __forceinline__ float wsum(float v) {
#pragma unroll
  for (int off = 32; off > 0; off >>= 1) v += __shfl_xor(v, off, 64);
  return v;
}
__device__ __forceinline__ float wmax(float v) {
#pragma unroll
  for (int off = 32; off > 0; off >>= 1) v = fmaxf(v, __shfl_xor(v, off, 64));
  return v;
}

// K0: Wqkv f32 [c][576] -> Wb bf16 [j][c] row-major
__global__ __launch_bounds__(256) void k0_wconv(const float* __restrict__ Wqkv, ushort* __restrict__ Wb) {
  int j0 = blockIdx.x * 64, c0 = blockIdx.y * 64;
  __shared__ float L[64][65];
  int t = threadIdx.x;
#pragma unroll
  for (int p = 0; p < 4; ++p) {
    int idx = t + 256 * p;
    int row = idx >> 4, col = (idx & 15) << 2;   // row = c, col = j
    float4 v = *reinterpret_cast<const float4*>(&Wqkv[(size_t)(c0 + row) * 576 + j0 + col]);
    L[row][col] = v.x; L[row][col + 1] = v.y; L[row][col + 2] = v.z; L[row][col + 3] = v.w;
  }
  __syncthreads();
#pragma unroll
  for (int p = 0; p < 4; ++p) {
    int idx = t + 256 * p;
    int jrow = idx >> 4, c4 = (idx & 15) << 2;
    ushort4 o;
    o.x = f2bf(L[c4 + 0][jrow]);
    o.y = f2bf(L[c4 + 1][jrow]);
    o.z = f2bf(L[c4 + 2][jrow]);
    o.w = f2bf(L[c4 + 3][jrow]);
    *reinterpret_cast<ushort4*>(&Wb[(size_t)(j0 + jrow) * CCH + c0 + c4]) = o;
  }
}

// K12: fused transpose + full qkv GEMM per 32-n slab (512 blocks/batch for TLP).
__global__ __launch_bounds__(256, 2) void k12_qkv(
    const float* __restrict__ x, const ushort* __restrict__ Wb,
    ushort* __restrict__ Tqk2, ushort* __restrict__ Vt2, float* __restrict__ norm2p)
{
  int z = blockIdx.y;
  const float* xb = x + (size_t)z * CCH * HWN;
  ushort* Tb2 = Tqk2 + (size_t)z * 384 * HWN;
  ushort* Vb2 = Vt2 + (size_t)z * HWN * CCH;
  float* npb = norm2p + (size_t)z * 512 * 384;
  int nt = blockIdx.x;            // 512 slabs of 32 n
  int n0 = nt * 32;
  __shared__ __align__(16) ushort SM[6400];   // 12.8 KB: FR (6144 ush) / Ep overlay (6400)
  ushort* FR = SM;
  int t = threadIdx.x, l = t & 63, w = t >> 6;
  int lg = l >> 4, lr = l & 15;

  // ---- stage x -> FR: thread = (n = t&31, c-group = t>>5); 3 tiles; 24 indep loads
  {
    int nl = t & 31, cg = t >> 5;
    const float* xrow = xb + n0 + nl;
    int frbase = (nl >> 4) * 3072 + (nl & 15) * 8;
#pragma unroll
    for (int tile = 0; tile < 3; ++tile) {
      int chunk = tile * 8 + cg;
      int c0 = chunk * 8;
      float v[8];
#pragma unroll
      for (int j = 0; j < 8; ++j)
        v[j] = xrow[(size_t)(c0 + j) * HWN];
      unsigned q0 = (unsigned)f2bf(v[0]) | ((unsigned)f2bf(v[1]) << 16);
      unsigned q1 = (unsigned)f2bf(v[2]) | ((unsigned)f2bf(v[3]) << 16);
      unsigned q2 = (unsigned)f2bf(v[4]) | ((unsigned)f2bf(v[5]) << 16);
      unsigned q3 = (unsigned)f2bf(v[6]) | ((unsigned)f2bf(v[7]) << 16);
      *reinterpret_cast<int4*>(&FR[frbase + chunk * 128]) = make_int4(q0, q1, q2, q3);
    }
  }
  __syncthreads();

  // ---- a-fragments (shared by all jt)
  bf16x8 a[6][2];
#pragma unroll
  for (int k = 0; k < 6; ++k)
#pragma unroll
    for (int m = 0; m < 2; ++m)
      a[k][m] = *reinterpret_cast<const bf16x8*>(&FR[m * 3072 + (4 * k + lg) * 128 + lr * 8]);

#pragma unroll
  for (int jt = 0; jt < 3; ++jt) {
    f32x4 acc[2][3] = {};
#pragma unroll
    for (int k = 0; k < 6; ++k) {
      bf16x8 b[3];
#pragma unroll
      for (int f = 0; f < 3; ++f)
        b[f] = *reinterpret_cast<const bf16x8*>(
            &Wb[(size_t)(jt * 192 + w * 48 + 16 * f + lr) * CCH + 32 * k + 8 * lg]);
#pragma unroll
      for (int m = 0; m < 2; ++m)
#pragma unroll
        for (int f = 0; f < 3; ++f)
          acc[m][f] = __builtin_amdgcn_mfma_f32_16x16x32_bf16(a[k][m], b[f], acc[m][f], 0, 0, 0);
    }

    if (jt == 2) {
      // V: LDS transpose Ep[32 n][200 c] -> swizzled Vt2
      __syncthreads();           // all waves past a-reads & jt 0/1
      ushort* Ep = SM;
#pragma unroll
      for (int m = 0; m < 2; ++m)
#pragma unroll
        for (int f = 0; f < 3; ++f) {
          int cl = w * 48 + 16 * f + lr;
          int nb = 16 * m + 4 * lg;
#pragma unroll
          for (int r = 0; r < 4; ++r)
            Ep[(nb + r) * 200 + cl] = f2bf(acc[m][f][r]);
        }
      __syncthreads();
      int nblk = nt * 2;
#pragma unroll
      for (int p = 0; p < 3; ++p) {
        int ii = t + 256 * p;              // 0..767 = 2 n16 x 24 cg x 16 nq
        int nq = ii & 15, n16 = ii / 384, cg = (ii - n16 * 384) >> 4;
        int4 v = *reinterpret_cast<const int4*>(&Ep[(n16 * 16 + nq) * 200 + cg * 8]);
        size_t off = (size_t)(nblk + n16) * (16 * CCH) + cg * 128 + nq * 8;
        *reinterpret_cast<int4*>(&Vb2[off]) = v;
      }
    } else {
      // q/k: norms + direct packed stores (r=0..3 contiguous n)
      int jb16 = jt * 12 + 3 * w;
#pragma unroll
      for (int f = 0; f < 3; ++f) {
        float sq = 0.f;
#pragma unroll
        for (int m = 0; m < 2; ++m)
#pragma unroll
          for (int r = 0; r < 4; ++r) sq += acc[m][f][r] * acc[m][f][r];
        sq += __shfl_xor(sq, 16, 64);
        sq += __shfl_xor(sq, 32, 64);
        if (lg == 0) {
          int j = jt * 192 + w * 48 + 16 * f + lr;
          npb[(size_t)nt * 384 + j] = sq;
        }
#pragma unroll
        for (int m = 0; m < 2; ++m) {
          uint2 pk;
          pk.x = (unsigned)f2bf(acc[m][f][0]) | ((unsigned)f2bf(acc[m][f][1]) << 16);
          pk.y = (unsigned)f2bf(acc[m][f][2]) | ((unsigned)f2bf(acc[m][f][3]) << 16);
          size_t off = (size_t)(jb16 + f) * (16 * HWN) +
                       (size_t)(nt * 4 + 2 * m + (lg >> 1)) * 128 + lr * 8 + 4 * (lg & 1);
          *reinterpret_cast<uint2*>(&Tb2[off]) = pk;
        }
      }
    }
  }
}

// K3: invn[j] = 1/max(sqrt(sum over 512 slabs of norm2p), eps)
__global__ __launch_bounds__(256) void k3_invn(const float* __restrict__ norm2p, float* __restrict__ invn) {
  int z = blockIdx.y, j = blockIdx.x;
  const float* npb = norm2p + (size_t)z * 512 * 384;
  int t = threadIdx.x;
  float s = npb[(size_t)t * 384 + j] + npb[(size_t)(t + 256) * 384 + j];
  s = wsum(s);
  __shared__ float red[4];
  if ((t & 63) == 0) red[t >> 6] = s;
  __syncthreads();
  if (t == 0) {
    float tot = red[0] + red[1] + red[2] + red[3];
    invn[(size_t)z * 384 + j] = 1.f / fmaxf(sqrtf(tot), 1e-12f);
  }
}

// K4: Gpart[chunk][c][d] = sum over n-chunk of K[c][n]*Q[d][n]. SPLIT=32.
__global__ __launch_bounds__(256) void k4_gram(const ushort* __restrict__ Tqk2, float* __restrict__ Gpart) {
  int z = blockIdx.z;
  const ushort* Tb2 = Tqk2 + (size_t)z * 384 * HWN;
  float* Gb = Gpart + (size_t)z * SPLIT * CCH * CCH;
  int tile = blockIdx.x, chunk = blockIdx.y;
  int ct = tile / 3, dt = tile % 3;
  int t = threadIdx.x, l = t & 63, w = t >> 6;
  int wc = w >> 1, wd = w & 1, lg = l >> 4, lr = l & 15;
  f32x4 acc[2][2] = {};
  for (int s = 0; s < 8; ++s) {
    int nco = chunk * 64 + s * 8;
#pragma unroll
    for (int hh = 0; hh < 2; ++hh) {
      int ko = nco + 4 * hh + lg;
      bf16x8 a[2], bb[2];
#pragma unroll
      for (int m = 0; m < 2; ++m)
        a[m] = *reinterpret_cast<const bf16x8*>(
            &Tb2[(size_t)(12 + 4 * ct + 2 * wc + m) * (16 * HWN) + (size_t)ko * 128 + lr * 8]);
#pragma unroll
      for (int f = 0; f < 2; ++f)
        bb[f] = *reinterpret_cast<const bf16x8*>(
            &Tb2[(size_t)(4 * dt + 2 * wd + f) * (16 * HWN) + (size_t)ko * 128 + lr * 8]);
#pragma unroll
      for (int m = 0; m < 2; ++m)
#pragma unroll
        for (int f = 0; f < 2; ++f)
          acc[m][f] = __builtin_amdgcn_mfma_f32_16x16x32_bf16(a[m], bb[f], acc[m][f], 0, 0, 0);
    }
  }
#pragma unroll
  for (int m = 0; m < 2; ++m)
#pragma unroll
    for (int f = 0; f < 2; ++f)
#pragma unroll
      for (int r = 0; r < 4; ++r)
        Gb[(size_t)(chunk * CCH + ct * 64 + 32 * wc + 16 * m + 4 * lg + r) * CCH +
           dt * 64 + 32 * wd + 16 * f + lr] = acc[m][f][r];
}

// K5: reduce Gpart over 32 chunks, scale, softmax over d -> S
__global__ __launch_bounds__(64) void k5_softmax(
    const float* __restrict__ Gpart, const float* __restrict__ invn,
    const float* __restrict__ sigma, float* __restrict__ S)
{
  int c = blockIdx.x, z = blockIdx.y;
  const float* Gb = Gpart + (size_t)z * SPLIT * CCH * CCH;
  const float* inb = invn + (size_t)z * 384;
  float sig = sigma[0];
  float ink = inb[192 + c];
  float lv[3];
#pragma unroll
  for (int r = 0; r < 3; ++r) {
    int d = threadIdx.x + 64 * r;
    float s = 0.f;
    for (int ch = 0; ch < SPLIT; ++ch)
      s += Gb[(size_t)(ch * CCH + c) * CCH + d];
    lv[r] = s * ink * inb[d] * sig;
  }
  float m = fmaxf(lv[0], fmaxf(lv[1], lv[2]));
  m = wmax(m);
  float e[3], tot = 0.f;
#pragma unroll
  for (int r = 0; r < 3; ++r) { e[r] = __expf(lv[r] - m); tot += e[r]; }
  tot = wsum(tot);
  float inv = 1.f / tot;
  float* Sb = S + (size_t)z * CCH * CCH;
#pragma unroll
  for (int r = 0; r < 3; ++r) Sb[(size_t)c * CCH + threadIdx.x + 64 * r] = e[r] * inv;
}

// K6: Mt[e][c] = sum_d S[c][d] * Wlin[d][e]  (bf16 out, row-major, for K7 B-side)
__global__ __launch_bounds__(192) void k6_mlin(
    const float* __restrict__ S, const float* __restrict__ Wlin, ushort* __restrict__ Mt)
{
  int z = blockIdx.y, c = blockIdx.x, e = threadIdx.x;
  const float* Sb = S + (size_t)z * CCH * CCH;
  float s = 0.f;
  for (int d = 0; d < CCH; ++d) s += Sb[(size_t)c * CCH + d] * Wlin[(size_t)d * CCH + e];
  Mt[(size_t)z * CCH * CCH + (size_t)e * CCH + c] = f2bf(s);
}

// K7: out[e][n] = sum_c Mt[e][c] * Vt2[n][c]. 32-n blocks (512/batch), LDS-free.
// wave w covers e = w*48 + 16f + lr (all 192 e across 4 waves), all 32 n.
__global__ __launch_bounds__(256, 4) void k7_out(
    const ushort* __restrict__ Mt, const ushort* __restrict__ Vt2, float* __restrict__ out)
{
  int z = blockIdx.y;
  const ushort* Mb = Mt + (size_t)z * CCH * CCH;
  const ushort* Vb2 = Vt2 + (size_t)z * HWN * CCH;
  float* ob = out + (size_t)z * CCH * HWN;
  int nt = blockIdx.x;
  int n0 = nt * 32, nblk = nt * 2;
  int t = threadIdx.x, l = t & 63, w = t >> 6;
  int lg = l >> 4, lr = l & 15;
  f32x4 acc[2][3] = {};   // [ng][f]: n = 16ng+4lg+r, e = w*48+16f+lr
#pragma unroll
  for (int h = 0; h < 2; ++h)
#pragma unroll
    for (int k3 = 0; k3 < 3; ++k3) {
      bf16x8 an[2], mf[3];
#pragma unroll
      for (int ng = 0; ng < 2; ++ng)
        an[ng] = *reinterpret_cast<const bf16x8*>(
            &Vb2[(size_t)(nblk + ng) * (16 * CCH) + (12 * h + 4 * k3 + lg) * 128 + lr * 8]);
#pragma unroll
      for (int f = 0; f < 3; ++f)
        mf[f] = *reinterpret_cast<const bf16x8*>(
            &Mb[(size_t)(w * 48 + 16 * f + lr) * CCH + 96 * h + 32 * k3 + 8 * lg]);
#pragma unroll
      for (int ng = 0; ng < 2; ++ng)
#pragma unroll
        for (int f = 0; f < 3; ++f)
          acc[ng][f] = __builtin_amdgcn_mfma_f32_16x16x32_bf16(an[ng], mf[f], acc[ng][f], 0, 0, 0);
    }
#pragma unroll
  for (int ng = 0; ng < 2; ++ng)
#pragma unroll
    for (int f = 0; f < 3; ++f)
      *reinterpret_cast<f32x4*>(
          &ob[(size_t)(w * 48 + 16 * f + lr) * HWN + n0 + 16 * ng + 4 * lg]) = acc[ng][f];
}

extern "C" void kernel_launch(void* const* d_in, const int* in_sizes, int n_in,
                              void* d_out, int out_size, void* d_ws, size_t ws_size,
                              hipStream_t stream) {
  const float* x     = (const float*)d_in[0];
  const float* Wqkv  = (const float*)d_in[1];
  const float* Wlin  = (const float*)d_in[2];
  const float* sigma = (const float*)d_in[3];
  float* out = (float*)d_out;

  const size_t wbElems = (size_t)576 * CCH;
  const size_t perB =
      (size_t)384 * HWN * 2 +          // Tqk2
      (size_t)HWN * CCH * 2 +          // Vt2
      (size_t)512 * 384 * 4 +          // norm2p
      (size_t)384 * 4 +                // invn
      (size_t)SPLIT * CCH * CCH * 4 +  // Gpart
      (size_t)CCH * CCH * 4 +          // S
      (size_t)CCH * CCH * 2;           // Mt
  int per = 4;
  while (per > 1 && ws_size < wbElems * 2 + (size_t)per * perB) per >>= 1;

  ushort* Wb = (ushort*)d_ws;
  k0_wconv<<<dim3(9, 3), 256, 0, stream>>>(Wqkv, Wb);

  for (int b0 = 0; b0 < NB; b0 += per) {
    char* base = (char*)d_ws + wbElems * 2;
    ushort* Tqk2 = (ushort*)base;
    ushort* Vt2  = Tqk2 + (size_t)per * 384 * HWN;
    float* norm2p = (float*)(Vt2 + (size_t)per * HWN * CCH);
    float* invn  = norm2p + (size_t)per * 512 * 384;
    float* Gpart = invn + (size_t)per * 384;
    float* S     = Gpart + (size_t)per * SPLIT * CCH * CCH;
    ushort* Mt   = (ushort*)(S + (size_t)per * CCH * CCH);
    const float* xb = x + (size_t)b0 * CCH * HWN;
    float* ob = out + (size_t)b0 * CCH * HWN;

    k12_qkv   <<<dim3(512, per), 256, 0, stream>>>(xb, Wb, Tqk2, Vt2, norm2p);
    k3_invn   <<<dim3(384, per), 256, 0, stream>>>(norm2p, invn);
    k4_gram   <<<dim3(9, SPLIT, per), 256, 0, stream>>>(Tqk2, Gpart);
    k5_softmax<<<dim3(192, per), 64, 0, stream>>>(Gpart, invn, sigma, S);
    k6_mlin   <<<dim3(192, per), 192, 0, stream>>>(S, Wlin, Mt);
    k7_out    <<<dim3(512, per), 256, 0, stream>>>(Mt, Vt2, ob);
  }
}

// Round 14
// 111.676 us; speedup vs baseline: 1.3248x; 1.3248x over previous
//
#include <hip/hip_runtime.h>
#include <hip/hip_bf16.h>

#define CCH 192
#define HWN 16384
#define NB  4
#define SPLIT 16

typedef __attribute__((ext_vector_type(8))) short bf16x8;
typedef __attribute__((ext_vector_type(4))) float f32x4;

// swizzled fragment-native layout for a [R rows][C cols] bf16 matrix:
//   idx(r,c) = (r>>4)*(16*C) + (c>>3)*128 + (r&15)*8 + (c&7)

__device__ __forceinline__ ushort f2bf(float f) {
  __hip_bfloat16 h = __float2bfloat16(f);   // HW RNE; backend can fuse to v_cvt_pk_bf16_f32
  return *reinterpret_cast<ushort*>(&h);
}

__device__ __forceinline__ float wsum(float v) {
#pragma unroll
  for (int off = 32; off > 0; off >>= 1) v += __shfl_xor(v, off, 64);
  return v;
}
__device__ __forceinline__ float wmax(float v) {
#pragma unroll
  for (int off = 32; off > 0; off >>= 1) v = fmaxf(v, __shfl_xor(v, off, 64));
  return v;
}

// K0: Wqkv f32 [c][576] -> Wb bf16 [j][c] row-major
__global__ __launch_bounds__(256) void k0_wconv(const float* __restrict__ Wqkv, ushort* __restrict__ Wb) {
  int j0 = blockIdx.x * 64, c0 = blockIdx.y * 64;
  __shared__ float L[64][65];
  int t = threadIdx.x;
#pragma unroll
  for (int p = 0; p < 4; ++p) {
    int idx = t + 256 * p;
    int row = idx >> 4, col = (idx & 15) << 2;   // row = c, col = j
    float4 v = *reinterpret_cast<const float4*>(&Wqkv[(size_t)(c0 + row) * 576 + j0 + col]);
    L[row][col] = v.x; L[row][col + 1] = v.y; L[row][col + 2] = v.z; L[row][col + 3] = v.w;
  }
  __syncthreads();
#pragma unroll
  for (int p = 0; p < 4; ++p) {
    int idx = t + 256 * p;
    int jrow = idx >> 4, c4 = (idx & 15) << 2;
    ushort4 o;
    o.x = f2bf(L[c4 + 0][jrow]);
    o.y = f2bf(L[c4 + 1][jrow]);
    o.z = f2bf(L[c4 + 2][jrow]);
    o.w = f2bf(L[c4 + 3][jrow]);
    *reinterpret_cast<ushort4*>(&Wb[(size_t)(j0 + jrow) * CCH + c0 + c4]) = o;
  }
}

// K12: fused transpose + FULL qkv GEMM per 64-n slab. Stage x once; q/k epilogues
// store DIRECT from acc (packed uint2, no LDS); only V uses the LDS transpose.
__global__ __launch_bounds__(256, 2) void k12_qkv(
    const float* __restrict__ x, const ushort* __restrict__ Wb,
    ushort* __restrict__ Tqk2, ushort* __restrict__ Vt2, float* __restrict__ norm2p)
{
  int z = blockIdx.y;
  const float* xb = x + (size_t)z * CCH * HWN;
  ushort* Tb2 = Tqk2 + (size_t)z * 384 * HWN;
  ushort* Vb2 = Vt2 + (size_t)z * HWN * CCH;
  float* npb = norm2p + (size_t)z * 256 * 384;
  int nt = blockIdx.x;
  int n0 = nt * 64;
  __shared__ __align__(16) ushort SM[13056];   // 26,112 B: FR (24,576 B); Ep overlays in jt==2
  ushort* FR = SM;
  int t = threadIdx.x, l = t & 63, w = t >> 6;   // w = j-group
  int lg = l >> 4, lr = l & 15;

  // ---- stage x -> FR once: wave w covers c-chunk tile*4+w, 6 tiles; 48 indep loads/thread
  {
    int nl = l;
    const float* xrow = xb + n0 + nl;
    int frbase = (nl >> 4) * 3072 + (nl & 15) * 8;
#pragma unroll
    for (int tile = 0; tile < 6; ++tile) {
      int chunk = tile * 4 + w;
      int c0 = chunk * 8;
      float v[8];
#pragma unroll
      for (int j = 0; j < 8; ++j)
        v[j] = xrow[(size_t)(c0 + j) * HWN];
      unsigned q0 = (unsigned)f2bf(v[0]) | ((unsigned)f2bf(v[1]) << 16);
      unsigned q1 = (unsigned)f2bf(v[2]) | ((unsigned)f2bf(v[3]) << 16);
      unsigned q2 = (unsigned)f2bf(v[4]) | ((unsigned)f2bf(v[5]) << 16);
      unsigned q3 = (unsigned)f2bf(v[6]) | ((unsigned)f2bf(v[7]) << 16);
      *reinterpret_cast<int4*>(&FR[frbase + chunk * 128]) = make_int4(q0, q1, q2, q3);
    }
  }
  __syncthreads();

  // ---- all a-fragments (shared by all jt)
  bf16x8 a[6][4];
#pragma unroll
  for (int k = 0; k < 6; ++k)
#pragma unroll
    for (int m = 0; m < 4; ++m)
      a[k][m] = *reinterpret_cast<const bf16x8*>(&FR[m * 3072 + (4 * k + lg) * 128 + lr * 8]);

#pragma unroll
  for (int jt = 0; jt < 3; ++jt) {
    f32x4 acc[4][3] = {};
#pragma unroll
    for (int k = 0; k < 6; ++k) {
      bf16x8 b[3];
#pragma unroll
      for (int f = 0; f < 3; ++f)
        b[f] = *reinterpret_cast<const bf16x8*>(
            &Wb[(size_t)(jt * 192 + w * 48 + 16 * f + lr) * CCH + 32 * k + 8 * lg]);
#pragma unroll
      for (int m = 0; m < 4; ++m)
#pragma unroll
        for (int f = 0; f < 3; ++f)
          acc[m][f] = __builtin_amdgcn_mfma_f32_16x16x32_bf16(a[k][m], b[f], acc[m][f], 0, 0, 0);
    }

    if (jt == 2) {
      // V: c = w*48+16f+lr -> Ep[64 n][200 c] -> swizzled Vt2 (LDS transpose needed:
      // acc's r-lanes are stride-8 apart in Vt2, not contiguous)
      __syncthreads();           // all waves done reading FR; Ep may overlay
      ushort* Ep = SM;
#pragma unroll
      for (int m = 0; m < 4; ++m)
#pragma unroll
        for (int f = 0; f < 3; ++f) {
          int cl = w * 48 + 16 * f + lr;
          int nb = 16 * m + 4 * lg;
#pragma unroll
          for (int r = 0; r < 4; ++r)
            Ep[(nb + r) * 200 + cl] = f2bf(acc[m][f][r]);
        }
      __syncthreads();
      int nblk = n0 >> 4;
#pragma unroll
      for (int p = 0; p < 6; ++p) {
        int ii = t + 256 * p;              // 0..1535 = 4 n16 x 24 cg x 16 nq
        int nq = ii & 15, n16 = ii / 384, cg = (ii - n16 * 384) >> 4;
        int4 v = *reinterpret_cast<const int4*>(&Ep[(n16 * 16 + nq) * 200 + cg * 8]);
        size_t off = (size_t)(nblk + n16) * (16 * CCH) + cg * 128 + nq * 8;
        *reinterpret_cast<int4*>(&Vb2[off]) = v;
      }
    } else {
      // q/k: norms + DIRECT packed stores. j&15 = lr; r=0..3 are contiguous n:
      // off = (jt*12+3w+f)*16*HWN + (nt*8+2m+(lg>>1))*128 + lr*8 + 4*(lg&1)
      int jb16 = jt * 12 + 3 * w;
#pragma unroll
      for (int f = 0; f < 3; ++f) {
        float sq = 0.f;
#pragma unroll
        for (int m = 0; m < 4; ++m)
#pragma unroll
          for (int r = 0; r < 4; ++r) sq += acc[m][f][r] * acc[m][f][r];
        sq += __shfl_xor(sq, 16, 64);
        sq += __shfl_xor(sq, 32, 64);
        if (lg == 0) {
          int j = jt * 192 + w * 48 + 16 * f + lr;
          npb[(size_t)nt * 384 + j] = sq;
        }
#pragma unroll
        for (int m = 0; m < 4; ++m) {
          uint2 pk;
          pk.x = (unsigned)f2bf(acc[m][f][0]) | ((unsigned)f2bf(acc[m][f][1]) << 16);
          pk.y = (unsigned)f2bf(acc[m][f][2]) | ((unsigned)f2bf(acc[m][f][3]) << 16);
          size_t off = (size_t)(jb16 + f) * (16 * HWN) +
                       (size_t)(nt * 8 + 2 * m + (lg >> 1)) * 128 + lr * 8 + 4 * (lg & 1);
          *reinterpret_cast<uint2*>(&Tb2[off]) = pk;
        }
      }
    }
  }
}

// K3: invn[j] = 1/max(sqrt(sum_nb norm2p[nb][j]), eps)
__global__ __launch_bounds__(256) void k3_invn(const float* __restrict__ norm2p, float* __restrict__ invn) {
  int z = blockIdx.y, j = blockIdx.x;
  const float* npb = norm2p + (size_t)z * 256 * 384;
  int t = threadIdx.x;
  float s = npb[(size_t)t * 384 + j];
  s = wsum(s);
  __shared__ float red[4];
  if ((t & 63) == 0) red[t >> 6] = s;
  __syncthreads();
  if (t == 0) {
    float tot = red[0] + red[1] + red[2] + red[3];
    invn[(size_t)z * 384 + j] = 1.f / fmaxf(sqrtf(tot), 1e-12f);
  }
}

// K4: Gpart[chunk][c][d] = sum over n-chunk of K[c][n]*Q[d][n]. LDS-free, direct frag loads.
__global__ __launch_bounds__(256) void k4_gram(const ushort* __restrict__ Tqk2, float* __restrict__ Gpart) {
  int z = blockIdx.z;
  const ushort* Tb2 = Tqk2 + (size_t)z * 384 * HWN;
  float* Gb = Gpart + (size_t)z * SPLIT * CCH * CCH;
  int tile = blockIdx.x, chunk = blockIdx.y;
  int ct = tile / 3, dt = tile % 3;
  int t = threadIdx.x, l = t & 63, w = t >> 6;
  int wc = w >> 1, wd = w & 1, lg = l >> 4, lr = l & 15;
  f32x4 acc[2][2] = {};
  for (int s = 0; s < 16; ++s) {
    int nco = chunk * 128 + s * 8;
#pragma unroll
    for (int hh = 0; hh < 2; ++hh) {
      int ko = nco + 4 * hh + lg;
      bf16x8 a[2], bb[2];
#pragma unroll
      for (int m = 0; m < 2; ++m)
        a[m] = *reinterpret_cast<const bf16x8*>(
            &Tb2[(size_t)(12 + 4 * ct + 2 * wc + m) * (16 * HWN) + (size_t)ko * 128 + lr * 8]);
#pragma unroll
      for (int f = 0; f < 2; ++f)
        bb[f] = *reinterpret_cast<const bf16x8*>(
            &Tb2[(size_t)(4 * dt + 2 * wd + f) * (16 * HWN) + (size_t)ko * 128 + lr * 8]);
#pragma unroll
      for (int m = 0; m < 2; ++m)
#pragma unroll
        for (int f = 0; f < 2; ++f)
          acc[m][f] = __builtin_amdgcn_mfma_f32_16x16x32_bf16(a[m], bb[f], acc[m][f], 0, 0, 0);
    }
  }
#pragma unroll
  for (int m = 0; m < 2; ++m)
#pragma unroll
    for (int f = 0; f < 2; ++f)
#pragma unroll
      for (int r = 0; r < 4; ++r)
        Gb[(size_t)(chunk * CCH + ct * 64 + 32 * wc + 16 * m + 4 * lg + r) * CCH +
           dt * 64 + 32 * wd + 16 * f + lr] = acc[m][f][r];
}

// K5: reduce Gpart over chunks, scale, softmax over d -> S
__global__ __launch_bounds__(64) void k5_softmax(
    const float* __restrict__ Gpart, const float* __restrict__ invn,
    const float* __restrict__ sigma, float* __restrict__ S)
{
  int c = blockIdx.x, z = blockIdx.y;
  const float* Gb = Gpart + (size_t)z * SPLIT * CCH * CCH;
  const float* inb = invn + (size_t)z * 384;
  float sig = sigma[0];
  float ink = inb[192 + c];
  float lv[3];
#pragma unroll
  for (int r = 0; r < 3; ++r) {
    int d = threadIdx.x + 64 * r;
    float s = 0.f;
    for (int ch = 0; ch < SPLIT; ++ch)
      s += Gb[(size_t)(ch * CCH + c) * CCH + d];
    lv[r] = s * ink * inb[d] * sig;
  }
  float m = fmaxf(lv[0], fmaxf(lv[1], lv[2]));
  m = wmax(m);
  float e[3], tot = 0.f;
#pragma unroll
  for (int r = 0; r < 3; ++r) { e[r] = __expf(lv[r] - m); tot += e[r]; }
  tot = wsum(tot);
  float inv = 1.f / tot;
  float* Sb = S + (size_t)z * CCH * CCH;
#pragma unroll
  for (int r = 0; r < 3; ++r) Sb[(size_t)c * CCH + threadIdx.x + 64 * r] = e[r] * inv;
}

// K6: Mt[e][c] = sum_d S[c][d] * Wlin[d][e]  (bf16 out, row-major, for K7 B-side)
__global__ __launch_bounds__(192) void k6_mlin(
    const float* __restrict__ S, const float* __restrict__ Wlin, ushort* __restrict__ Mt)
{
  int z = blockIdx.y, c = blockIdx.x, e = threadIdx.x;
  const float* Sb = S + (size_t)z * CCH * CCH;
  float s = 0.f;
  for (int d = 0; d < CCH; ++d) s += Sb[(size_t)c * CCH + d] * Wlin[(size_t)d * CCH + e];
  Mt[(size_t)z * CCH * CCH + (size_t)e * CCH + c] = f2bf(s);
}

// K7: out[e][n] = sum_c Mt[e][c] * Vt2[n][c]. All 3 e-tiles in one block.
__global__ __launch_bounds__(256, 2) void k7_out(
    const ushort* __restrict__ Mt, const ushort* __restrict__ Vt2, float* __restrict__ out)
{
  int z = blockIdx.y;
  const ushort* Mb = Mt + (size_t)z * CCH * CCH;
  const ushort* Vb2 = Vt2 + (size_t)z * HWN * CCH;
  float* ob = out + (size_t)z * CCH * HWN;
  int nt = blockIdx.x;
  int n0 = nt * 128;
  int t = threadIdx.x, l = t & 63, w = t >> 6;
  int wn = w >> 1, we = w & 1, lg = l >> 4, lr = l & 15;
  int nblk = n0 >> 4;
  f32x4 acc[3][4][2] = {};   // [et][ng][mg]
#pragma unroll
  for (int h = 0; h < 2; ++h)
#pragma unroll
    for (int k3 = 0; k3 < 3; ++k3) {
      bf16x8 an[4];
#pragma unroll
      for (int ng = 0; ng < 4; ++ng)
        an[ng] = *reinterpret_cast<const bf16x8*>(
            &Vb2[(size_t)(nblk + 4 * wn + ng) * (16 * CCH) + (12 * h + 4 * k3 + lg) * 128 + lr * 8]);
#pragma unroll
      for (int et = 0; et < 3; ++et) {
        bf16x8 mf[2];
#pragma unroll
        for (int mg = 0; mg < 2; ++mg)
          mf[mg] = *reinterpret_cast<const bf16x8*>(
              &Mb[(size_t)(et * 64 + 32 * we + 16 * mg + lr) * CCH + 96 * h + 32 * k3 + 8 * lg]);
#pragma unroll
        for (int ng = 0; ng < 4; ++ng)
#pragma unroll
          for (int mg = 0; mg < 2; ++mg)
            acc[et][ng][mg] = __builtin_amdgcn_mfma_f32_16x16x32_bf16(an[ng], mf[mg], acc[et][ng][mg], 0, 0, 0);
      }
    }
#pragma unroll
  for (int et = 0; et < 3; ++et)
#pragma unroll
    for (int ng = 0; ng < 4; ++ng)
#pragma unroll
      for (int mg = 0; mg < 2; ++mg)
        *reinterpret_cast<f32x4*>(
            &ob[(size_t)(et * 64 + 32 * we + 16 * mg + lr) * HWN + n0 + 64 * wn + 16 * ng + 4 * lg]) = acc[et][ng][mg];
}

extern "C" void kernel_launch(void* const* d_in, const int* in_sizes, int n_in,
                              void* d_out, int out_size, void* d_ws, size_t ws_size,
                              hipStream_t stream) {
  const float* x     = (const float*)d_in[0];
  const float* Wqkv  = (const float*)d_in[1];
  const float* Wlin  = (const float*)d_in[2];
  const float* sigma = (const float*)d_in[3];
  float* out = (float*)d_out;

  const size_t wbElems = (size_t)576 * CCH;
  const size_t perB =
      (size_t)384 * HWN * 2 +          // Tqk2
      (size_t)HWN * CCH * 2 +          // Vt2
      (size_t)256 * 384 * 4 +          // norm2p
      (size_t)384 * 4 +                // invn
      (size_t)SPLIT * CCH * CCH * 4 +  // Gpart
      (size_t)CCH * CCH * 4 +          // S
      (size_t)CCH * CCH * 2;           // Mt
  int per = 4;
  while (per > 1 && ws_size < wbElems * 2 + (size_t)per * perB) per >>= 1;

  ushort* Wb = (ushort*)d_ws;
  k0_wconv<<<dim3(9, 3), 256, 0, stream>>>(Wqkv, Wb);

  for (int b0 = 0; b0 < NB; b0 += per) {
    char* base = (char*)d_ws + wbElems * 2;
    ushort* Tqk2 = (ushort*)base;
    ushort* Vt2  = Tqk2 + (size_t)per * 384 * HWN;
    float* norm2p = (float*)(Vt2 + (size_t)per * HWN * CCH);
    float* invn  = norm2p + (size_t)per * 256 * 384;
    float* Gpart = invn + (size_t)per * 384;
    float* S     = Gpart + (size_t)per * SPLIT * CCH * CCH;
    ushort* Mt   = (ushort*)(S + (size_t)per * CCH * CCH);
    const float* xb = x + (size_t)b0 * CCH * HWN;
    float* ob = out + (size_t)b0 * CCH * HWN;

    k12_qkv   <<<dim3(256, per), 256, 0, stream>>>(xb, Wb, Tqk2, Vt2, norm2p);
    k3_invn   <<<dim3(384, per), 256, 0, stream>>>(norm2p, invn);
    k4_gram   <<<dim3(9, SPLIT, per), 256, 0, stream>>>(Tqk2, Gpart);
    k5_softmax<<<dim3(192, per), 64, 0, stream>>>(Gpart, invn, sigma, S);
    k6_mlin   <<<dim3(192, per), 192, 0, stream>>>(S, Wlin, Mt);
    k7_out    <<<dim3(128, per), 256, 0, stream>>>(Mt, Vt2, ob);
  }
}

// Round 15
// 111.666 us; speedup vs baseline: 1.3250x; 1.0001x over previous
//
#include <hip/hip_runtime.h>
#include <hip/hip_bf16.h>

#define CCH 192
#define HWN 16384
#define NB  4
#define SPLIT 16

typedef __attribute__((ext_vector_type(8))) short bf16x8;
typedef __attribute__((ext_vector_type(4))) float f32x4;

// swizzled fragment-native layout for a [R rows][C cols] bf16 matrix:
//   idx(r,c) = (r>>4)*(16*C) + (c>>3)*128 + (r&15)*8 + (c&7)

__device__ __forceinline__ ushort f2bf(float f) {
  __hip_bfloat16 h = __float2bfloat16(f);   // HW RNE; backend fuses to v_cvt_pk_bf16_f32
  return *reinterpret_cast<ushort*>(&h);
}

__device__ __forceinline__ void gload_lds16(const void* g, void* l) {
  __builtin_amdgcn_global_load_lds(
      (const __attribute__((address_space(1))) void*)g,
      (__attribute__((address_space(3))) void*)l, 16, 0, 0);
}

__device__ __forceinline__ float wsum(float v) {
#pragma unroll
  for (int off = 32; off > 0; off >>= 1) v += __shfl_xor(v, off, 64);
  return v;
}
__device__ __forceinline__ float wmax(float v) {
#pragma unroll
  for (int off = 32; off > 0; off >>= 1) v = fmaxf(v, __shfl_xor(v, off, 64));
  return v;
}

// K0: Wqkv f32 [c][576] -> Wb bf16 [j][c] row-major
__global__ __launch_bounds__(256) void k0_wconv(const float* __restrict__ Wqkv, ushort* __restrict__ Wb) {
  int j0 = blockIdx.x * 64, c0 = blockIdx.y * 64;
  __shared__ float L[64][65];
  int t = threadIdx.x;
#pragma unroll
  for (int p = 0; p < 4; ++p) {
    int idx = t + 256 * p;
    int row = idx >> 4, col = (idx & 15) << 2;   // row = c, col = j
    float4 v = *reinterpret_cast<const float4*>(&Wqkv[(size_t)(c0 + row) * 576 + j0 + col]);
    L[row][col] = v.x; L[row][col + 1] = v.y; L[row][col + 2] = v.z; L[row][col + 3] = v.w;
  }
  __syncthreads();
#pragma unroll
  for (int p = 0; p < 4; ++p) {
    int idx = t + 256 * p;
    int jrow = idx >> 4, c4 = (idx & 15) << 2;
    ushort4 o;
    o.x = f2bf(L[c4 + 0][jrow]);
    o.y = f2bf(L[c4 + 1][jrow]);
    o.z = f2bf(L[c4 + 2][jrow]);
    o.w = f2bf(L[c4 + 3][jrow]);
    *reinterpret_cast<ushort4*>(&Wb[(size_t)(j0 + jrow) * CCH + c0 + c4]) = o;
  }
}

// K12: fused transpose + FULL qkv GEMM per 64-n slab.
// Stage x -> LDS fp32 via global_load_lds (fire-and-forget, no VGPR round-trip),
// convert once to swizzled bf16 FRbf, then identical MFMA + epilogues as before.
__global__ __launch_bounds__(256, 2) void k12_qkv(
    const float* __restrict__ x, const ushort* __restrict__ Wb,
    ushort* __restrict__ Tqk2, ushort* __restrict__ Vt2, float* __restrict__ norm2p)
{
  int z = blockIdx.y;
  const float* xb = x + (size_t)z * CCH * HWN;
  ushort* Tb2 = Tqk2 + (size_t)z * 384 * HWN;
  ushort* Vb2 = Vt2 + (size_t)z * HWN * CCH;
  float* npb = norm2p + (size_t)z * 256 * 384;
  int nt = blockIdx.x;
  int n0 = nt * 64;
  __shared__ __align__(16) float  FR32[192 * 64];   // 49,152 B; Ep overlays in jt==2
  __shared__ __align__(16) ushort FRbf[12288];      // 24,576 B swizzled bf16 frags
  int t = threadIdx.x, l = t & 63, w = t >> 6;      // w = j-group / c-quarter
  int lg = l >> 4, lr = l & 15;

  // ---- stage x -> FR32 [c][64 n] fp32: 12 width-16 global_load_lds per wave.
  // lane i covers x[c0+(i>>4)][n0+4(i&15)..+3] -> LDS base+16i == FR32[c][n] linear.
  {
    int i16 = l >> 4, nq4 = (l & 15) << 2;
#pragma unroll
    for (int q = 0; q < 12; ++q) {
      int c0 = w * 48 + q * 4;
      const float* g = xb + (size_t)(c0 + i16) * HWN + n0 + nq4;
      gload_lds16(g, &FR32[c0 * 64]);
    }
  }
  __syncthreads();   // drains vmcnt

  // ---- convert FR32 -> FRbf (swizzled frag layout), conflict-free ds_read_b32
  {
    int nl = l;
    int frbase = (nl >> 4) * 3072 + (nl & 15) * 8;
#pragma unroll
    for (int tile = 0; tile < 6; ++tile) {
      int chunk = tile * 4 + w;
      float v[8];
#pragma unroll
      for (int j = 0; j < 8; ++j)
        v[j] = FR32[(chunk * 8 + j) * 64 + nl];
      unsigned q0 = (unsigned)f2bf(v[0]) | ((unsigned)f2bf(v[1]) << 16);
      unsigned q1 = (unsigned)f2bf(v[2]) | ((unsigned)f2bf(v[3]) << 16);
      unsigned q2 = (unsigned)f2bf(v[4]) | ((unsigned)f2bf(v[5]) << 16);
      unsigned q3 = (unsigned)f2bf(v[6]) | ((unsigned)f2bf(v[7]) << 16);
      *reinterpret_cast<int4*>(&FRbf[frbase + chunk * 128]) = make_int4(q0, q1, q2, q3);
    }
  }
  __syncthreads();

  // ---- all a-fragments (shared by all jt)
  bf16x8 a[6][4];
#pragma unroll
  for (int k = 0; k < 6; ++k)
#pragma unroll
    for (int m = 0; m < 4; ++m)
      a[k][m] = *reinterpret_cast<const bf16x8*>(&FRbf[m * 3072 + (4 * k + lg) * 128 + lr * 8]);

#pragma unroll
  for (int jt = 0; jt < 3; ++jt) {
    f32x4 acc[4][3] = {};
#pragma unroll
    for (int k = 0; k < 6; ++k) {
      bf16x8 b[3];
#pragma unroll
      for (int f = 0; f < 3; ++f)
        b[f] = *reinterpret_cast<const bf16x8*>(
            &Wb[(size_t)(jt * 192 + w * 48 + 16 * f + lr) * CCH + 32 * k + 8 * lg]);
#pragma unroll
      for (int m = 0; m < 4; ++m)
#pragma unroll
        for (int f = 0; f < 3; ++f)
          acc[m][f] = __builtin_amdgcn_mfma_f32_16x16x32_bf16(a[k][m], b[f], acc[m][f], 0, 0, 0);
    }

    if (jt == 2) {
      // V: c = w*48+16f+lr -> Ep[64 n][200 c] (overlays FR32) -> swizzled Vt2
      __syncthreads();
      ushort* Ep = reinterpret_cast<ushort*>(FR32);
#pragma unroll
      for (int m = 0; m < 4; ++m)
#pragma unroll
        for (int f = 0; f < 3; ++f) {
          int cl = w * 48 + 16 * f + lr;
          int nb = 16 * m + 4 * lg;
#pragma unroll
          for (int r = 0; r < 4; ++r)
            Ep[(nb + r) * 200 + cl] = f2bf(acc[m][f][r]);
        }
      __syncthreads();
      int nblk = n0 >> 4;
#pragma unroll
      for (int p = 0; p < 6; ++p) {
        int ii = t + 256 * p;              // 0..1535 = 4 n16 x 24 cg x 16 nq
        int nq = ii & 15, n16 = ii / 384, cg = (ii - n16 * 384) >> 4;
        int4 v = *reinterpret_cast<const int4*>(&Ep[(n16 * 16 + nq) * 200 + cg * 8]);
        size_t off = (size_t)(nblk + n16) * (16 * CCH) + cg * 128 + nq * 8;
        *reinterpret_cast<int4*>(&Vb2[off]) = v;
      }
    } else {
      // q/k: norms + DIRECT packed stores. j&15 = lr; r=0..3 contiguous n:
      // off = (jt*12+3w+f)*16*HWN + (nt*8+2m+(lg>>1))*128 + lr*8 + 4*(lg&1)
      int jb16 = jt * 12 + 3 * w;
#pragma unroll
      for (int f = 0; f < 3; ++f) {
        float sq = 0.f;
#pragma unroll
        for (int m = 0; m < 4; ++m)
#pragma unroll
          for (int r = 0; r < 4; ++r) sq += acc[m][f][r] * acc[m][f][r];
        sq += __shfl_xor(sq, 16, 64);
        sq += __shfl_xor(sq, 32, 64);
        if (lg == 0) {
          int j = jt * 192 + w * 48 + 16 * f + lr;
          npb[(size_t)nt * 384 + j] = sq;
        }
#pragma unroll
        for (int m = 0; m < 4; ++m) {
          uint2 pk;
          pk.x = (unsigned)f2bf(acc[m][f][0]) | ((unsigned)f2bf(acc[m][f][1]) << 16);
          pk.y = (unsigned)f2bf(acc[m][f][2]) | ((unsigned)f2bf(acc[m][f][3]) << 16);
          size_t off = (size_t)(jb16 + f) * (16 * HWN) +
                       (size_t)(nt * 8 + 2 * m + (lg >> 1)) * 128 + lr * 8 + 4 * (lg & 1);
          *reinterpret_cast<uint2*>(&Tb2[off]) = pk;
        }
      }
    }
  }
}

// K3: invn[j] = 1/max(sqrt(sum_nb norm2p[nb][j]), eps)
__global__ __launch_bounds__(256) void k3_invn(const float* __restrict__ norm2p, float* __restrict__ invn) {
  int z = blockIdx.y, j = blockIdx.x;
  const float* npb = norm2p + (size_t)z * 256 * 384;
  int t = threadIdx.x;
  float s = npb[(size_t)t * 384 + j];
  s = wsum(s);
  __shared__ float red[4];
  if ((t & 63) == 0) red[t >> 6] = s;
  __syncthreads();
  if (t == 0) {
    float tot = red[0] + red[1] + red[2] + red[3];
    invn[(size_t)z * 384 + j] = 1.f / fmaxf(sqrtf(tot), 1e-12f);
  }
}

// K4: Gpart[chunk][c][d] = sum over n-chunk of K[c][n]*Q[d][n]. LDS-free, direct frag loads.
__global__ __launch_bounds__(256) void k4_gram(const ushort* __restrict__ Tqk2, float* __restrict__ Gpart) {
  int z = blockIdx.z;
  const ushort* Tb2 = Tqk2 + (size_t)z * 384 * HWN;
  float* Gb = Gpart + (size_t)z * SPLIT * CCH * CCH;
  int tile = blockIdx.x, chunk = blockIdx.y;
  int ct = tile / 3, dt = tile % 3;
  int t = threadIdx.x, l = t & 63, w = t >> 6;
  int wc = w >> 1, wd = w & 1, lg = l >> 4, lr = l & 15;
  f32x4 acc[2][2] = {};
  for (int s = 0; s < 16; ++s) {
    int nco = chunk * 128 + s * 8;
#pragma unroll
    for (int hh = 0; hh < 2; ++hh) {
      int ko = nco + 4 * hh + lg;
      bf16x8 a[2], bb[2];
#pragma unroll
      for (int m = 0; m < 2; ++m)
        a[m] = *reinterpret_cast<const bf16x8*>(
            &Tb2[(size_t)(12 + 4 * ct + 2 * wc + m) * (16 * HWN) + (size_t)ko * 128 + lr * 8]);
#pragma unroll
      for (int f = 0; f < 2; ++f)
        bb[f] = *reinterpret_cast<const bf16x8*>(
            &Tb2[(size_t)(4 * dt + 2 * wd + f) * (16 * HWN) + (size_t)ko * 128 + lr * 8]);
#pragma unroll
      for (int m = 0; m < 2; ++m)
#pragma unroll
        for (int f = 0; f < 2; ++f)
          acc[m][f] = __builtin_amdgcn_mfma_f32_16x16x32_bf16(a[m], bb[f], acc[m][f], 0, 0, 0);
    }
  }
#pragma unroll
  for (int m = 0; m < 2; ++m)
#pragma unroll
    for (int f = 0; f < 2; ++f)
#pragma unroll
      for (int r = 0; r < 4; ++r)
        Gb[(size_t)(chunk * CCH + ct * 64 + 32 * wc + 16 * m + 4 * lg + r) * CCH +
           dt * 64 + 32 * wd + 16 * f + lr] = acc[m][f][r];
}

// K5: reduce Gpart over chunks, scale, softmax over d -> S
__global__ __launch_bounds__(64) void k5_softmax(
    const float* __restrict__ Gpart, const float* __restrict__ invn,
    const float* __restrict__ sigma, float* __restrict__ S)
{
  int c = blockIdx.x, z = blockIdx.y;
  const float* Gb = Gpart + (size_t)z * SPLIT * CCH * CCH;
  const float* inb = invn + (size_t)z * 384;
  float sig = sigma[0];
  float ink = inb[192 + c];
  float lv[3];
#pragma unroll
  for (int r = 0; r < 3; ++r) {
    int d = threadIdx.x + 64 * r;
    float s = 0.f;
    for (int ch = 0; ch < SPLIT; ++ch)
      s += Gb[(size_t)(ch * CCH + c) * CCH + d];
    lv[r] = s * ink * inb[d] * sig;
  }
  float m = fmaxf(lv[0], fmaxf(lv[1], lv[2]));
  m = wmax(m);
  float e[3], tot = 0.f;
#pragma unroll
  for (int r = 0; r < 3; ++r) { e[r] = __expf(lv[r] - m); tot += e[r]; }
  tot = wsum(tot);
  float inv = 1.f / tot;
  float* Sb = S + (size_t)z * CCH * CCH;
#pragma unroll
  for (int r = 0; r < 3; ++r) Sb[(size_t)c * CCH + threadIdx.x + 64 * r] = e[r] * inv;
}

// K6: Mt[e][c] = sum_d S[c][d] * Wlin[d][e]  (bf16 out, row-major, for K7 B-side)
__global__ __launch_bounds__(192) void k6_mlin(
    const float* __restrict__ S, const float* __restrict__ Wlin, ushort* __restrict__ Mt)
{
  int z = blockIdx.y, c = blockIdx.x, e = threadIdx.x;
  const float* Sb = S + (size_t)z * CCH * CCH;
  float s = 0.f;
  for (int d = 0; d < CCH; ++d) s += Sb[(size_t)c * CCH + d] * Wlin[(size_t)d * CCH + e];
  Mt[(size_t)z * CCH * CCH + (size_t)e * CCH + c] = f2bf(s);
}

// K7: out[e][n] = sum_c Mt[e][c] * Vt2[n][c]. All 3 e-tiles in one block.
__global__ __launch_bounds__(256, 2) void k7_out(
    const ushort* __restrict__ Mt, const ushort* __restrict__ Vt2, float* __restrict__ out)
{
  int z = blockIdx.y;
  const ushort* Mb = Mt + (size_t)z * CCH * CCH;
  const ushort* Vb2 = Vt2 + (size_t)z * HWN * CCH;
  float* ob = out + (size_t)z * CCH * HWN;
  int nt = blockIdx.x;
  int n0 = nt * 128;
  int t = threadIdx.x, l = t & 63, w = t >> 6;
  int wn = w >> 1, we = w & 1, lg = l >> 4, lr = l & 15;
  int nblk = n0 >> 4;
  f32x4 acc[3][4][2] = {};   // [et][ng][mg]
#pragma unroll
  for (int h = 0; h < 2; ++h)
#pragma unroll
    for (int k3 = 0; k3 < 3; ++k3) {
      bf16x8 an[4];
#pragma unroll
      for (int ng = 0; ng < 4; ++ng)
        an[ng] = *reinterpret_cast<const bf16x8*>(
            &Vb2[(size_t)(nblk + 4 * wn + ng) * (16 * CCH) + (12 * h + 4 * k3 + lg) * 128 + lr * 8]);
#pragma unroll
      for (int et = 0; et < 3; ++et) {
        bf16x8 mf[2];
#pragma unroll
        for (int mg = 0; mg < 2; ++mg)
          mf[mg] = *reinterpret_cast<const bf16x8*>(
              &Mb[(size_t)(et * 64 + 32 * we + 16 * mg + lr) * CCH + 96 * h + 32 * k3 + 8 * lg]);
#pragma unroll
        for (int ng = 0; ng < 4; ++ng)
#pragma unroll
          for (int mg = 0; mg < 2; ++mg)
            acc[et][ng][mg] = __builtin_amdgcn_mfma_f32_16x16x32_bf16(an[ng], mf[mg], acc[et][ng][mg], 0, 0, 0);
      }
    }
#pragma unroll
  for (int et = 0; et < 3; ++et)
#pragma unroll
    for (int ng = 0; ng < 4; ++ng)
#pragma unroll
      for (int mg = 0; mg < 2; ++mg)
        *reinterpret_cast<f32x4*>(
            &ob[(size_t)(et * 64 + 32 * we + 16 * mg + lr) * HWN + n0 + 64 * wn + 16 * ng + 4 * lg]) = acc[et][ng][mg];
}

extern "C" void kernel_launch(void* const* d_in, const int* in_sizes, int n_in,
                              void* d_out, int out_size, void* d_ws, size_t ws_size,
                              hipStream_t stream) {
  const float* x     = (const float*)d_in[0];
  const float* Wqkv  = (const float*)d_in[1];
  const float* Wlin  = (const float*)d_in[2];
  const float* sigma = (const float*)d_in[3];
  float* out = (float*)d_out;

  const size_t wbElems = (size_t)576 * CCH;
  const size_t perB =
      (size_t)384 * HWN * 2 +          // Tqk2
      (size_t)HWN * CCH * 2 +          // Vt2
      (size_t)256 * 384 * 4 +          // norm2p
      (size_t)384 * 4 +                // invn
      (size_t)SPLIT * CCH * CCH * 4 +  // Gpart
      (size_t)CCH * CCH * 4 +          // S
      (size_t)CCH * CCH * 2;           // Mt
  int per = 4;
  while (per > 1 && ws_size < wbElems * 2 + (size_t)per * perB) per >>= 1;

  ushort* Wb = (ushort*)d_ws;
  k0_wconv<<<dim3(9, 3), 256, 0, stream>>>(Wqkv, Wb);

  for (int b0 = 0; b0 < NB; b0 += per) {
    char* base = (char*)d_ws + wbElems * 2;
    ushort* Tqk2 = (ushort*)base;
    ushort* Vt2  = Tqk2 + (size_t)per * 384 * HWN;
    float* norm2p = (float*)(Vt2 + (size_t)per * HWN * CCH);
    float* invn  = norm2p + (size_t)per * 256 * 384;
    float* Gpart = invn + (size_t)per * 384;
    float* S     = Gpart + (size_t)per * SPLIT * CCH * CCH;
    ushort* Mt   = (ushort*)(S + (size_t)per * CCH * CCH);
    const float* xb = x + (size_t)b0 * CCH * HWN;
    float* ob = out + (size_t)b0 * CCH * HWN;

    k12_qkv   <<<dim3(256, per), 256, 0, stream>>>(xb, Wb, Tqk2, Vt2, norm2p);
    k3_invn   <<<dim3(384, per), 256, 0, stream>>>(norm2p, invn);
    k4_gram   <<<dim3(9, SPLIT, per), 256, 0, stream>>>(Tqk2, Gpart);
    k5_softmax<<<dim3(192, per), 64, 0, stream>>>(Gpart, invn, sigma, S);
    k6_mlin   <<<dim3(192, per), 192, 0, stream>>>(S, Wlin, Mt);
    k7_out    <<<dim3(128, per), 256, 0, stream>>>(Mt, Vt2, ob);
  }
}

// Round 16
// 111.627 us; speedup vs baseline: 1.3254x; 1.0004x over previous
//
#include <hip/hip_runtime.h>
#include <hip/hip_bf16.h>

#define CCH 192
#define HWN 16384
#define NB  4
#define SPLIT 16

typedef __attribute__((ext_vector_type(8))) short bf16x8;
typedef __attribute__((ext_vector_type(4))) float f32x4;

// swizzled fragment-native layout for a [R rows][C cols] bf16 matrix:
//   idx(r,c) = (r>>4)*(16*C) + (c>>3)*128 + (r&15)*8 + (c&7)

__device__ __forceinline__ ushort f2bf(float f) {
  __hip_bfloat16 h = __float2bfloat16(f);
  return *reinterpret_cast<ushort*>(&h);
}

__device__ __forceinline__ float wsum(float v) {
#pragma unroll
  for (int off = 32; off > 0; off >>= 1) v += __shfl_xor(v, off, 64);
  return v;
}
__device__ __forceinline__ float wmax(float v) {
#pragma unroll
  for (int off = 32; off > 0; off >>= 1) v = fmaxf(v, __shfl_xor(v, off, 64));
  return v;
}

// K0: Wqkv f32 [c][576] -> Wb bf16 [j][c] row-major
__global__ __launch_bounds__(256) void k0_wconv(const float* __restrict__ Wqkv, ushort* __restrict__ Wb) {
  int j0 = blockIdx.x * 64, c0 = blockIdx.y * 64;
  __shared__ float L[64][65];
  int t = threadIdx.x;
#pragma unroll
  for (int p = 0; p < 4; ++p) {
    int idx = t + 256 * p;
    int row = idx >> 4, col = (idx & 15) << 2;   // row = c, col = j
    float4 v = *reinterpret_cast<const float4*>(&Wqkv[(size_t)(c0 + row) * 576 + j0 + col]);
    L[row][col] = v.x; L[row][col + 1] = v.y; L[row][col + 2] = v.z; L[row][col + 3] = v.w;
  }
  __syncthreads();
#pragma unroll
  for (int p = 0; p < 4; ++p) {
    int idx = t + 256 * p;
    int jrow = idx >> 4, c4 = (idx & 15) << 2;
    ushort4 o;
    o.x = f2bf(L[c4 + 0][jrow]);
    o.y = f2bf(L[c4 + 1][jrow]);
    o.z = f2bf(L[c4 + 2][jrow]);
    o.w = f2bf(L[c4 + 3][jrow]);
    *reinterpret_cast<ushort4*>(&Wb[(size_t)(j0 + jrow) * CCH + c0 + c4]) = o;
  }
}

// K12: fused transpose + FULL qkv GEMM per 64-n slab.
// a-fragments re-read from LDS per jt (no 96-reg cache) + launch_bounds(256,4)
// => fits 4 blocks/CU in the unified VGPR/AGPR file => TLP hides phase stalls.
__global__ __launch_bounds__(256, 4) void k12_qkv(
    const float* __restrict__ x, const ushort* __restrict__ Wb,
    ushort* __restrict__ Tqk2, ushort* __restrict__ Vt2, float* __restrict__ norm2p)
{
  int z = blockIdx.y;
  const float* xb = x + (size_t)z * CCH * HWN;
  ushort* Tb2 = Tqk2 + (size_t)z * 384 * HWN;
  ushort* Vb2 = Vt2 + (size_t)z * HWN * CCH;
  float* npb = norm2p + (size_t)z * 256 * 384;
  int nt = blockIdx.x;
  int n0 = nt * 64;
  __shared__ __align__(16) ushort SM[13056];   // 26,112 B: FR (24,576 B); Ep overlays in jt==2
  ushort* FR = SM;
  int t = threadIdx.x, l = t & 63, w = t >> 6;   // w = j-group / c-quarter
  int lg = l >> 4, lr = l & 15;

  // ---- stage x -> FR once: wave w covers c-chunk tile*4+w, 6 tiles; 48 indep loads/thread
  {
    int nl = l;
    const float* xrow = xb + n0 + nl;
    int frbase = (nl >> 4) * 3072 + (nl & 15) * 8;
#pragma unroll
    for (int tile = 0; tile < 6; ++tile) {
      int chunk = tile * 4 + w;
      int c0 = chunk * 8;
      float v[8];
#pragma unroll
      for (int j = 0; j < 8; ++j)
        v[j] = xrow[(size_t)(c0 + j) * HWN];
      unsigned q0 = (unsigned)f2bf(v[0]) | ((unsigned)f2bf(v[1]) << 16);
      unsigned q1 = (unsigned)f2bf(v[2]) | ((unsigned)f2bf(v[3]) << 16);
      unsigned q2 = (unsigned)f2bf(v[4]) | ((unsigned)f2bf(v[5]) << 16);
      unsigned q3 = (unsigned)f2bf(v[6]) | ((unsigned)f2bf(v[7]) << 16);
      *reinterpret_cast<int4*>(&FR[frbase + chunk * 128]) = make_int4(q0, q1, q2, q3);
    }
  }
  __syncthreads();

#pragma unroll
  for (int jt = 0; jt < 3; ++jt) {
    f32x4 acc[4][3] = {};
#pragma unroll
    for (int k = 0; k < 6; ++k) {
      bf16x8 a[4], b[3];
#pragma unroll
      for (int m = 0; m < 4; ++m)
        a[m] = *reinterpret_cast<const bf16x8*>(&FR[m * 3072 + (4 * k + lg) * 128 + lr * 8]);
#pragma unroll
      for (int f = 0; f < 3; ++f)
        b[f] = *reinterpret_cast<const bf16x8*>(
            &Wb[(size_t)(jt * 192 + w * 48 + 16 * f + lr) * CCH + 32 * k + 8 * lg]);
#pragma unroll
      for (int m = 0; m < 4; ++m)
#pragma unroll
        for (int f = 0; f < 3; ++f)
          acc[m][f] = __builtin_amdgcn_mfma_f32_16x16x32_bf16(a[m], b[f], acc[m][f], 0, 0, 0);
    }

    if (jt == 2) {
      // V: c = w*48+16f+lr -> Ep[64 n][200 c] (overlays FR, dead now) -> swizzled Vt2
      __syncthreads();           // all waves done with FR a-reads
      ushort* Ep = SM;
#pragma unroll
      for (int m = 0; m < 4; ++m)
#pragma unroll
        for (int f = 0; f < 3; ++f) {
          int cl = w * 48 + 16 * f + lr;
          int nb = 16 * m + 4 * lg;
#pragma unroll
          for (int r = 0; r < 4; ++r)
            Ep[(nb + r) * 200 + cl] = f2bf(acc[m][f][r]);
        }
      __syncthreads();
      int nblk = n0 >> 4;
#pragma unroll
      for (int p = 0; p < 6; ++p) {
        int ii = t + 256 * p;              // 0..1535 = 4 n16 x 24 cg x 16 nq
        int nq = ii & 15, n16 = ii / 384, cg = (ii - n16 * 384) >> 4;
        int4 v = *reinterpret_cast<const int4*>(&Ep[(n16 * 16 + nq) * 200 + cg * 8]);
        size_t off = (size_t)(nblk + n16) * (16 * CCH) + cg * 128 + nq * 8;
        *reinterpret_cast<int4*>(&Vb2[off]) = v;
      }
    } else {
      // q/k: norms + DIRECT packed stores. j&15 = lr; r=0..3 contiguous n:
      // off = (jt*12+3w+f)*16*HWN + (nt*8+2m+(lg>>1))*128 + lr*8 + 4*(lg&1)
      int jb16 = jt * 12 + 3 * w;
#pragma unroll
      for (int f = 0; f < 3; ++f) {
        float sq = 0.f;
#pragma unroll
        for (int m = 0; m < 4; ++m)
#pragma unroll
          for (int r = 0; r < 4; ++r) sq += acc[m][f][r] * acc[m][f][r];
        sq += __shfl_xor(sq, 16, 64);
        sq += __shfl_xor(sq, 32, 64);
        if (lg == 0) {
          int j = jt * 192 + w * 48 + 16 * f + lr;
          npb[(size_t)nt * 384 + j] = sq;
        }
#pragma unroll
        for (int m = 0; m < 4; ++m) {
          uint2 pk;
          pk.x = (unsigned)f2bf(acc[m][f][0]) | ((unsigned)f2bf(acc[m][f][1]) << 16);
          pk.y = (unsigned)f2bf(acc[m][f][2]) | ((unsigned)f2bf(acc[m][f][3]) << 16);
          size_t off = (size_t)(jb16 + f) * (16 * HWN) +
                       (size_t)(nt * 8 + 2 * m + (lg >> 1)) * 128 + lr * 8 + 4 * (lg & 1);
          *reinterpret_cast<uint2*>(&Tb2[off]) = pk;
        }
      }
    }
  }
}

// K3: invn[j] = 1/max(sqrt(sum_nb norm2p[nb][j]), eps)
__global__ __launch_bounds__(256) void k3_invn(const float* __restrict__ norm2p, float* __restrict__ invn) {
  int z = blockIdx.y, j = blockIdx.x;
  const float* npb = norm2p + (size_t)z * 256 * 384;
  int t = threadIdx.x;
  float s = npb[(size_t)t * 384 + j];
  s = wsum(s);
  __shared__ float red[4];
  if ((t & 63) == 0) red[t >> 6] = s;
  __syncthreads();
  if (t == 0) {
    float tot = red[0] + red[1] + red[2] + red[3];
    invn[(size_t)z * 384 + j] = 1.f / fmaxf(sqrtf(tot), 1e-12f);
  }
}

// K4: Gpart[chunk][c][d] = sum over n-chunk of K[c][n]*Q[d][n]. LDS-free, direct frag loads.
__global__ __launch_bounds__(256) void k4_gram(const ushort* __restrict__ Tqk2, float* __restrict__ Gpart) {
  int z = blockIdx.z;
  const ushort* Tb2 = Tqk2 + (size_t)z * 384 * HWN;
  float* Gb = Gpart + (size_t)z * SPLIT * CCH * CCH;
  int tile = blockIdx.x, chunk = blockIdx.y;
  int ct = tile / 3, dt = tile % 3;
  int t = threadIdx.x, l = t & 63, w = t >> 6;
  int wc = w >> 1, wd = w & 1, lg = l >> 4, lr = l & 15;
  f32x4 acc[2][2] = {};
  for (int s = 0; s < 16; ++s) {
    int nco = chunk * 128 + s * 8;
#pragma unroll
    for (int hh = 0; hh < 2; ++hh) {
      int ko = nco + 4 * hh + lg;
      bf16x8 a[2], bb[2];
#pragma unroll
      for (int m = 0; m < 2; ++m)
        a[m] = *reinterpret_cast<const bf16x8*>(
            &Tb2[(size_t)(12 + 4 * ct + 2 * wc + m) * (16 * HWN) + (size_t)ko * 128 + lr * 8]);
#pragma unroll
      for (int f = 0; f < 2; ++f)
        bb[f] = *reinterpret_cast<const bf16x8*>(
            &Tb2[(size_t)(4 * dt + 2 * wd + f) * (16 * HWN) + (size_t)ko * 128 + lr * 8]);
#pragma unroll
      for (int m = 0; m < 2; ++m)
#pragma unroll
        for (int f = 0; f < 2; ++f)
          acc[m][f] = __builtin_amdgcn_mfma_f32_16x16x32_bf16(a[m], bb[f], acc[m][f], 0, 0, 0);
    }
  }
#pragma unroll
  for (int m = 0; m < 2; ++m)
#pragma unroll
    for (int f = 0; f < 2; ++f)
#pragma unroll
      for (int r = 0; r < 4; ++r)
        Gb[(size_t)(chunk * CCH + ct * 64 + 32 * wc + 16 * m + 4 * lg + r) * CCH +
           dt * 64 + 32 * wd + 16 * f + lr] = acc[m][f][r];
}

// K5: reduce Gpart over chunks, scale, softmax over d -> S
__global__ __launch_bounds__(64) void k5_softmax(
    const float* __restrict__ Gpart, const float* __restrict__ invn,
    const float* __restrict__ sigma, float* __restrict__ S)
{
  int c = blockIdx.x, z = blockIdx.y;
  const float* Gb = Gpart + (size_t)z * SPLIT * CCH * CCH;
  const float* inb = invn + (size_t)z * 384;
  float sig = sigma[0];
  float ink = inb[192 + c];
  float lv[3];
#pragma unroll
  for (int r = 0; r < 3; ++r) {
    int d = threadIdx.x + 64 * r;
    float s = 0.f;
    for (int ch = 0; ch < SPLIT; ++ch)
      s += Gb[(size_t)(ch * CCH + c) * CCH + d];
    lv[r] = s * ink * inb[d] * sig;
  }
  float m = fmaxf(lv[0], fmaxf(lv[1], lv[2]));
  m = wmax(m);
  float e[3], tot = 0.f;
#pragma unroll
  for (int r = 0; r < 3; ++r) { e[r] = __expf(lv[r] - m); tot += e[r]; }
  tot = wsum(tot);
  float inv = 1.f / tot;
  float* Sb = S + (size_t)z * CCH * CCH;
#pragma unroll
  for (int r = 0; r < 3; ++r) Sb[(size_t)c * CCH + threadIdx.x + 64 * r] = e[r] * inv;
}

// K6: Mt[e][c] = sum_d S[c][d] * Wlin[d][e]  (bf16 out, row-major, for K7 B-side)
__global__ __launch_bounds__(192) void k6_mlin(
    const float* __restrict__ S, const float* __restrict__ Wlin, ushort* __restrict__ Mt)
{
  int z = blockIdx.y, c = blockIdx.x, e = threadIdx.x;
  const float* Sb = S + (size_t)z * CCH * CCH;
  float s = 0.f;
  for (int d = 0; d < CCH; ++d) s += Sb[(size_t)c * CCH + d] * Wlin[(size_t)d * CCH + e];
  Mt[(size_t)z * CCH * CCH + (size_t)e * CCH + c] = f2bf(s);
}

// K7: out[e][n] = sum_c Mt[e][c] * Vt2[n][c]. All 3 e-tiles in one block.
__global__ __launch_bounds__(256, 2) void k7_out(
    const ushort* __restrict__ Mt, const ushort* __restrict__ Vt2, float* __restrict__ out)
{
  int z = blockIdx.y;
  const ushort* Mb = Mt + (size_t)z * CCH * CCH;
  const ushort* Vb2 = Vt2 + (size_t)z * HWN * CCH;
  float* ob = out + (size_t)z * CCH * HWN;
  int nt = blockIdx.x;
  int n0 = nt * 128;
  int t = threadIdx.x, l = t & 63, w = t >> 6;
  int wn = w >> 1, we = w & 1, lg = l >> 4, lr = l & 15;
  int nblk = n0 >> 4;
  f32x4 acc[3][4][2] = {};   // [et][ng][mg]
#pragma unroll
  for (int h = 0; h < 2; ++h)
#pragma unroll
    for (int k3 = 0; k3 < 3; ++k3) {
      bf16x8 an[4];
#pragma unroll
      for (int ng = 0; ng < 4; ++ng)
        an[ng] = *reinterpret_cast<const bf16x8*>(
            &Vb2[(size_t)(nblk + 4 * wn + ng) * (16 * CCH) + (12 * h + 4 * k3 + lg) * 128 + lr * 8]);
#pragma unroll
      for (int et = 0; et < 3; ++et) {
        bf16x8 mf[2];
#pragma unroll
        for (int mg = 0; mg < 2; ++mg)
          mf[mg] = *reinterpret_cast<const bf16x8*>(
              &Mb[(size_t)(et * 64 + 32 * we + 16 * mg + lr) * CCH + 96 * h + 32 * k3 + 8 * lg]);
#pragma unroll
        for (int ng = 0; ng < 4; ++ng)
#pragma unroll
          for (int mg = 0; mg < 2; ++mg)
            acc[et][ng][mg] = __builtin_amdgcn_mfma_f32_16x16x32_bf16(an[ng], mf[mg], acc[et][ng][mg], 0, 0, 0);
      }
    }
#pragma unroll
  for (int et = 0; et < 3; ++et)
#pragma unroll
    for (int ng = 0; ng < 4; ++ng)
#pragma unroll
      for (int mg = 0; mg < 2; ++mg)
        *reinterpret_cast<f32x4*>(
            &ob[(size_t)(et * 64 + 32 * we + 16 * mg + lr) * HWN + n0 + 64 * wn + 16 * ng + 4 * lg]) = acc[et][ng][mg];
}

extern "C" void kernel_launch(void* const* d_in, const int* in_sizes, int n_in,
                              void* d_out, int out_size, void* d_ws, size_t ws_size,
                              hipStream_t stream) {
  const float* x     = (const float*)d_in[0];
  const float* Wqkv  = (const float*)d_in[1];
  const float* Wlin  = (const float*)d_in[2];
  const float* sigma = (const float*)d_in[3];
  float* out = (float*)d_out;

  const size_t wbElems = (size_t)576 * CCH;
  const size_t perB =
      (size_t)384 * HWN * 2 +          // Tqk2
      (size_t)HWN * CCH * 2 +          // Vt2
      (size_t)256 * 384 * 4 +          // norm2p
      (size_t)384 * 4 +                // invn
      (size_t)SPLIT * CCH * CCH * 4 +  // Gpart
      (size_t)CCH * CCH * 4 +          // S
      (size_t)CCH * CCH * 2;           // Mt
  int per = 4;
  while (per > 1 && ws_size < wbElems * 2 + (size_t)per * perB) per >>= 1;

  ushort* Wb = (ushort*)d_ws;
  k0_wconv<<<dim3(9, 3), 256, 0, stream>>>(Wqkv, Wb);

  for (int b0 = 0; b0 < NB; b0 += per) {
    char* base = (char*)d_ws + wbElems * 2;
    ushort* Tqk2 = (ushort*)base;
    ushort* Vt2  = Tqk2 + (size_t)per * 384 * HWN;
    float* norm2p = (float*)(Vt2 + (size_t)per * HWN * CCH);
    float* invn  = norm2p + (size_t)per * 256 * 384;
    float* Gpart = invn + (size_t)per * 384;
    float* S     = Gpart + (size_t)per * SPLIT * CCH * CCH;
    ushort* Mt   = (ushort*)(S + (size_t)per * CCH * CCH);
    const float* xb = x + (size_t)b0 * CCH * HWN;
    float* ob = out + (size_t)b0 * CCH * HWN;

    k12_qkv   <<<dim3(256, per), 256, 0, stream>>>(xb, Wb, Tqk2, Vt2, norm2p);
    k3_invn   <<<dim3(384, per), 256, 0, stream>>>(norm2p, invn);
    k4_gram   <<<dim3(9, SPLIT, per), 256, 0, stream>>>(Tqk2, Gpart);
    k5_softmax<<<dim3(192, per), 64, 0, stream>>>(Gpart, invn, sigma, S);
    k6_mlin   <<<dim3(192, per), 192, 0, stream>>>(S, Wlin, Mt);
    k7_out    <<<dim3(128, per), 256, 0, stream>>>(Mt, Vt2, ob);
  }
}